// Round 3
// baseline (215.500 us; speedup 1.0000x reference)
//
#include <hip/hip_runtime.h>
#include <hip/hip_bf16.h>

typedef unsigned short u16;
typedef unsigned int u32;
typedef __attribute__((ext_vector_type(8))) short bf16x8;
typedef __attribute__((ext_vector_type(16))) float f32x16;
typedef __attribute__((ext_vector_type(4))) int int4v;
typedef __attribute__((ext_vector_type(4))) float f32x4;

#define CIN 128
#define COUT 128
#define HWSZ 4096
#define RC 16
#define EPS 1e-5f

__device__ __forceinline__ float b2f(u16 u) {
    u32 v = ((u32)u) << 16;
    union { u32 i; float f; } c; c.i = v; return c.f;
}

__device__ __forceinline__ void dma16(const void* g, void* l) {
    __builtin_amdgcn_global_load_lds((const __attribute__((address_space(1))) void*)g,
                                     (__attribute__((address_space(3))) void*)l, 16, 0, 0);
}

// ---------------- Kernel 1: transpose x -> xT bf16 (pre-swizzled) + exp(logits) + sum ----------------
// xT row g = b*4096 + y*64 + xs holds 128 ci bf16 (256B); 16B chunk c stored at c ^ (xs&7).
__global__ __launch_bounds__(256) void k_xform(const float* __restrict__ x,
                                               const float* __restrict__ mask_w,
                                               const float* __restrict__ mask_b,
                                               u16* __restrict__ xT,
                                               float* __restrict__ attn,
                                               float* __restrict__ sumexp) {
    int y = blockIdx.x, b = blockIdx.y, t = threadIdx.x;
    __shared__ float tile[128 * 65];
    __shared__ float red[256];

    int c4 = t & 15, ci0 = t >> 4;
#pragma unroll
    for (int i = 0; i < 8; ++i) {
        int ci = ci0 + i * 16;
        f32x4 v = *(const f32x4*)(x + (size_t)(b * 128 + ci) * 4096 + y * 64 + c4 * 4);
        float* tr = tile + ci * 65 + c4 * 4;
        tr[0] = v.x; tr[1] = v.y; tr[2] = v.z; tr[3] = v.w;
    }
    __syncthreads();

    {
        int xs = t & 63, grp = t >> 6;
        float a = 0.f;
#pragma unroll 8
        for (int ci = grp * 32; ci < grp * 32 + 32; ++ci)
            a = fmaf(tile[ci * 65 + xs], mask_w[ci], a);
        red[grp * 64 + xs] = a;
    }

    {
        int xs = t >> 2, q = t & 3;
        u16* dst = xT + ((size_t)b * 4096 + y * 64 + xs) * 128;
        int sw = xs & 7;
#pragma unroll
        for (int k = 0; k < 4; ++k) {
            int cd = q * 4 + k;
            int cs = cd ^ sw;
            u16 tmp[8];
#pragma unroll
            for (int e = 0; e < 8; ++e) {
                __hip_bfloat16 h = __float2bfloat16(tile[(cd * 8 + e) * 65 + xs]);
                tmp[e] = *reinterpret_cast<u16*>(&h);
            }
            *(int4v*)(dst + cs * 8) = *(int4v*)tmp;
        }
    }
    __syncthreads();
    if (t < 64) {
        // logits are ~N(0, 0.23): exp without max-subtraction is numerically safe
        float e = __expf(red[t] + red[64 + t] + red[128 + t] + red[192 + t] + mask_b[0]);
        attn[b * HWSZ + y * 64 + t] = e;
        float s = e;
#pragma unroll
        for (int off = 32; off; off >>= 1) s += __shfl_down(s, off);
        if (t == 0) atomicAdd(&sumexp[b], s);
    }
}

// ---------------- Kernel 2: context = xT . e / S ----------------
__global__ __launch_bounds__(256) void k_context(const u16* __restrict__ xT,
                                                 const float* __restrict__ attn,
                                                 const float* __restrict__ sumexp,
                                                 float* __restrict__ ctx) {
    int bid = blockIdx.x;
    int b = bid >> 4, sc = bid & 15;
    int t = threadIdx.x;
    int px = t >> 4, cg = t & 15;
    const char* xb = (const char*)(xT + (size_t)b * HWSZ * 128);
    float acc[8] = {0.f, 0.f, 0.f, 0.f, 0.f, 0.f, 0.f, 0.f};
    int s0 = sc * 256 + px;
    int coff = (cg * 16) ^ ((px & 7) << 4);
    for (int j = 0; j < 16; ++j) {
        int s = s0 + j * 16;
        float e = attn[b * HWSZ + s];
        int4v u = *(const int4v*)(xb + (size_t)s * 256 + coff);
        const u16* q = (const u16*)&u;
#pragma unroll
        for (int k = 0; k < 8; ++k) acc[k] = fmaf(e, b2f(q[k]), acc[k]);
    }
    __shared__ float red[16][132];
#pragma unroll
    for (int k = 0; k < 8; ++k) red[px][cg * 8 + k] = acc[k];
    __syncthreads();
    if (t < 128) {
        float s = 0.f;
#pragma unroll
        for (int g = 0; g < 16; ++g) s += red[g][t];
        atomicAdd(&ctx[b * 128 + t], s / sumexp[b]);
    }
}

// ---------------- Kernel 3: transform (fused) + weight generation ----------------
// wgen[b][p] plane (32KB) laid out as 16B units: unit(co,c) = (co>>5)*512 + c*32 + (co&31),
// holding bf16 for ci octet c of output row co. (A-fragment-coalesced layout for k_conv.)
__global__ __launch_bounds__(256) void k_genw(const float* __restrict__ ctx,
                                              const float* __restrict__ t1_w,
                                              const float* __restrict__ t1_b,
                                              const float* __restrict__ ln_g,
                                              const float* __restrict__ ln_b,
                                              const float* __restrict__ t2_w,
                                              const float* __restrict__ t2_b,
                                              const float* __restrict__ fc_w,
                                              const float* __restrict__ fc_b,
                                              u16* __restrict__ wgen) {
    int bid = blockIdx.x;
    int b = bid >> 3, g = bid & 7;
    int t = threadIdx.x;
    __shared__ float ctx_sh[128];
    __shared__ float traw[RC];
    __shared__ float gate_sh[64];
    if (t < 128) ctx_sh[t] = ctx[b * 128 + t];
    __syncthreads();
    if (t < RC) {
        float a = 0.f;
        for (int c = 0; c < 128; ++c) a = fmaf(ctx_sh[c], t1_w[t * 128 + c], a);
        traw[t] = a + t1_b[t];
    }
    __syncthreads();
    int r32g = g >> 1;
    if (t < 64) {
        float tv[RC], mu = 0.f;
#pragma unroll
        for (int r = 0; r < RC; ++r) { tv[r] = traw[r]; mu += tv[r]; }
        mu *= (1.f / RC);
        float var = 0.f;
#pragma unroll
        for (int r = 0; r < RC; ++r) { float d = tv[r] - mu; var = fmaf(d, d, var); }
        var *= (1.f / RC);
        float rs = rsqrtf(var + EPS);
        int gi = r32g * 64 + t;
        float xw = 0.f;
#pragma unroll
        for (int r = 0; r < RC; ++r) {
            float a = fmaxf(0.f, fmaf((tv[r] - mu) * rs, ln_g[r], ln_b[r]));
            xw = fmaf(a, t2_w[gi * RC + r], xw);
        }
        xw += t2_b[gi];
        gate_sh[t] = 1.f / (1.f + __expf(-xw));
    }
    __syncthreads();
    int U = g * 256 + t;
    int r32 = U >> 9, c = (U >> 5) & 15, l31 = U & 31;
    int co = r32 * 32 + l31;
    float gate = gate_sh[l31 * 2 + (c >> 3)];
    int base = co * 1152 + c * 72;
    float wv[72], bv[72];
#pragma unroll
    for (int i = 0; i < 18; ++i) {
        *(f32x4*)&wv[i * 4] = *(const f32x4*)(fc_w + base + i * 4);
        *(f32x4*)&bv[i * 4] = *(const f32x4*)(fc_b + base + i * 4);
    }
    u16* wb = wgen + (size_t)b * 9 * 16384;
    int unit = r32 * 512 + c * 32 + l31;
#pragma unroll
    for (int p = 0; p < 9; ++p) {
        u16 tmp[8];
#pragma unroll
        for (int e = 0; e < 8; ++e) {
            float v = fmaf(wv[e * 9 + p], gate, bv[e * 9 + p]);
            __hip_bfloat16 h = __float2bfloat16(v);
            tmp[e] = *reinterpret_cast<u16*>(&h);
        }
        *(int4v*)(wb + p * 16384 + unit * 8) = *(int4v*)tmp;
    }
}

// ---------------- Kernel 4: per-sample 3x3 conv; A in registers, B via LDS DMA ----------------
__global__ __launch_bounds__(256, 2) void k_conv(const u16* __restrict__ xT,
                                                 const u16* __restrict__ wgen,
                                                 float* __restrict__ out) {
    __shared__ __align__(16) u16 Bt[132 * 128];   // rows r*66+xh, verbatim xT rows (swizzled by xs&7)

    int bid0 = blockIdx.x;
    int xcd = bid0 & 7, i5 = bid0 >> 3;
    int b = xcd * 4 + (i5 >> 5);
    int yp = i5 & 31, y0 = yp * 2;

    int t = threadIdx.x;
    int lane = t & 63, w = t >> 6;
    int wr = w >> 1, wc = w & 1;
    int l31 = lane & 31, l5 = lane >> 5;

    const char* xb = (const char*)(xT + (size_t)b * HWSZ * 128);
    const char* wbase = (const char*)(wgen + (size_t)b * 9 * 16384);
    // per-lane A base: plane p at wbase + p*32768; a0 row (wr*64+l31) chunk (2ks+l5)
    const char* abase = wbase + wr * 16384 + l5 * 512 + l31 * 16;

    bf16x8 RA[16], RB[16];
    f32x16 acc00 = {0}, acc01 = {0}, acc10 = {0}, acc11 = {0};
    const char* Bb = (const char*)Bt;
    int rowB0 = wc * 66 + l31;

#define LOADP(P, R)                                                        \
    {                                                                      \
        const char* ap = abase + (P) * 32768;                              \
        _Pragma("unroll") for (int ks = 0; ks < 8; ++ks) {                 \
            R[ks]     = *(const bf16x8*)(ap + ks * 1024);                  \
            R[8 + ks] = *(const bf16x8*)(ap + 8192 + ks * 1024);           \
        }                                                                  \
    }

#define COMPUTE(P, R)                                                              \
    {                                                                              \
        const int kw = (P) % 3;                                                    \
        int rB0 = (rowB0 + kw) << 8;                                               \
        int rB1 = rB0 + (32 << 8);                                                 \
        int sB = ((l31 + kw - 1) & 7) << 4;                                        \
        _Pragma("unroll") for (int ks = 0; ks < 8; ++ks) {                         \
            int kb = ks * 32 + l5 * 16;                                            \
            bf16x8 b0 = *(const bf16x8*)(Bb + (rB0 | (kb ^ sB)));                  \
            bf16x8 b1 = *(const bf16x8*)(Bb + (rB1 | (kb ^ sB)));                  \
            acc00 = __builtin_amdgcn_mfma_f32_32x32x16_bf16(R[ks], b0, acc00, 0, 0, 0);     \
            acc01 = __builtin_amdgcn_mfma_f32_32x32x16_bf16(R[ks], b1, acc01, 0, 0, 0);     \
            acc10 = __builtin_amdgcn_mfma_f32_32x32x16_bf16(R[8 + ks], b0, acc10, 0, 0, 0); \
            acc11 = __builtin_amdgcn_mfma_f32_32x32x16_bf16(R[8 + ks], b1, acc11, 0, 0, 0); \
        }                                                                          \
    }

#define STAGEB(KH)                                                                   \
    {                                                                                \
        _Pragma("unroll") for (int r = 0; r < 2; ++r) {                              \
            int y = y0 + r + (KH) - 1;                                               \
            char* base = (char*)Bt + (r * 66) * 256;                                 \
            if ((unsigned)y < 64u) {                                                 \
                const char* src = xb + (size_t)y * 64 * 256;                         \
                _Pragma("unroll") for (int i = 0; i < 4; ++i) {                      \
                    int off = (w * 4 + i) * 1024;                                    \
                    dma16(src + off + lane * 16, base + 256 + off);                  \
                }                                                                    \
                if (t < 32) {                                                        \
                    int hr = (t >> 4) * 65;                                          \
                    *(int4v*)(base + hr * 256 + (t & 15) * 16) = int4v{0, 0, 0, 0};  \
                }                                                                    \
            } else {                                                                 \
                for (int i = t; i < 1056; i += 256)                                  \
                    *(int4v*)(base + i * 16) = int4v{0, 0, 0, 0};                    \
            }                                                                        \
        }                                                                            \
    }

    LOADP(0, RA);
#pragma unroll
    for (int p = 0; p < 9; ++p) {
        if (p % 3 == 0) {
            __syncthreads();   // all waves done reading previous Bt
            STAGEB(p / 3);
            __syncthreads();   // Bt DMA + halo writes complete (drains vmcnt+lgkm)
        }
        if (p < 8) {
            if (p & 1) { LOADP(p + 1, RA); } else { LOADP(p + 1, RB); }
        }
        if (p & 1) { COMPUTE(p, RB); } else { COMPUTE(p, RA); }
    }

    // writeout: C/D layout col=lane&31, row=(reg&3)+8*(reg>>2)+4*(lane>>5)
    float* ob = out + (size_t)b * COUT * HWSZ;
    int y = y0 + wc;
    auto store_acc = [&](const f32x16& v, int m2, int n4) {
        float* colp = ob + (size_t)(wr * 64 + m2 * 32) * HWSZ + y * 64 + n4 * 32 + l31;
#pragma unroll
        for (int r = 0; r < 16; ++r) {
            int row32 = (r & 3) + ((r >> 2) << 3) + (l5 << 2);
            colp[(size_t)row32 * HWSZ] = v[r];
        }
    };
    store_acc(acc00, 0, 0);
    store_acc(acc01, 0, 1);
    store_acc(acc10, 1, 0);
    store_acc(acc11, 1, 1);
#undef LOADP
#undef COMPUTE
#undef STAGEB
}

extern "C" void kernel_launch(void* const* d_in, const int* in_sizes, int n_in,
                              void* d_out, int out_size, void* d_ws, size_t ws_size,
                              hipStream_t stream) {
    const float* x      = (const float*)d_in[0];
    const float* mask_w = (const float*)d_in[1];
    const float* mask_b = (const float*)d_in[2];
    const float* t1_w   = (const float*)d_in[3];
    const float* t1_b   = (const float*)d_in[4];
    const float* ln_g   = (const float*)d_in[5];
    const float* ln_b   = (const float*)d_in[6];
    const float* t2_w   = (const float*)d_in[7];
    const float* t2_b   = (const float*)d_in[8];
    const float* fc_w   = (const float*)d_in[9];
    const float* fc_b   = (const float*)d_in[10];
    float* out = (float*)d_out;

    char* ws = (char*)d_ws;
    u16*   xT     = (u16*)ws;                        // 33,554,432 B
    float* attn   = (float*)(ws + 33554432);         // 524,288 B (stores exp(logit))
    float* ctx    = (float*)(ws + 34078720);         // 16,384 B
    float* sumexp = (float*)(ws + 34095104);         // 128 B (padded to 1024)
    u16*   wgen   = (u16*)(ws + 34096128);           // 9,437,184 B

    hipMemsetAsync(ws + 34078720, 0, 17408, stream);  // zero ctx + sumexp

    k_xform  <<<dim3(64, 32), 256, 0, stream>>>(x, mask_w, mask_b, xT, attn, sumexp);
    k_context<<<512, 256, 0, stream>>>(xT, attn, sumexp, ctx);
    k_genw   <<<256, 256, 0, stream>>>(ctx, t1_w, t1_b, ln_g, ln_b,
                                       t2_w, t2_b, fc_w, fc_b, wgen);
    k_conv   <<<1024, 256, 0, stream>>>(xT, wgen, out);
}

// Round 6
// 209.886 us; speedup vs baseline: 1.0267x; 1.0267x over previous
//
#include <hip/hip_runtime.h>
#include <hip/hip_bf16.h>

typedef unsigned short u16;
typedef unsigned int u32;
typedef __attribute__((ext_vector_type(8))) short bf16x8;
typedef __attribute__((ext_vector_type(16))) float f32x16;
typedef __attribute__((ext_vector_type(4))) int int4v;
typedef __attribute__((ext_vector_type(4))) float f32x4;

#define CIN 128
#define COUT 128
#define HWSZ 4096
#define RC 16
#define EPS 1e-5f

__device__ __forceinline__ void dma16(const void* g, void* l) {
    __builtin_amdgcn_global_load_lds((const __attribute__((address_space(1))) void*)g,
                                     (__attribute__((address_space(3))) void*)l, 16, 0, 0);
}

// ---------------- Kernel 1: transpose x -> xT bf16 (pre-swizzled) + exp(logits) + ctxU partials ----
// xT row g = b*4096 + y*64 + xs holds 128 ci bf16 (256B); 16B chunk c stored at c ^ (xs&7).
// ctxU[b][c] += sum_xs exp(logit[xs]) * x[c][y][xs]  (unnormalized; /sumexp happens in k_genw)
__global__ __launch_bounds__(256) void k_xform(const float* __restrict__ x,
                                               const float* __restrict__ mask_w,
                                               const float* __restrict__ mask_b,
                                               u16* __restrict__ xT,
                                               float* __restrict__ ctxU,
                                               float* __restrict__ sumexp) {
    int y = blockIdx.x, b = blockIdx.y, t = threadIdx.x;
    __shared__ float tile[128 * 68];   // stride 68 floats: 16B-aligned rows
    __shared__ float red[256];
    __shared__ float e_sh[64];

    // load + transpose-in (vector 16B LDS writes)
    int c4 = t & 15, ci0 = t >> 4;
#pragma unroll
    for (int i = 0; i < 8; ++i) {
        int ci = ci0 + i * 16;
        f32x4 v = *(const f32x4*)(x + (size_t)(b * 128 + ci) * 4096 + y * 64 + c4 * 4);
        *(f32x4*)(tile + ci * 68 + c4 * 4) = v;
    }
    __syncthreads();

    // logits partials: wave grp covers 32 ci for all 64 xs
    {
        int xs = t & 63, grp = t >> 6;
        float a = 0.f;
#pragma unroll 8
        for (int ci = grp * 32; ci < grp * 32 + 32; ++ci)
            a = fmaf(tile[ci * 68 + xs], mask_w[ci], a);
        red[t] = a;
    }
    __syncthreads();
    if (t < 64) {
        // logits ~N(0,0.23): exp without max-subtraction is safe
        float e = __expf(red[t] + red[64 + t] + red[128 + t] + red[192 + t] + mask_b[0]);
        e_sh[t] = e;
        float s = e;
#pragma unroll
        for (int off = 32; off; off >>= 1) s += __shfl_down(s, off);
        if (t == 0) atomicAdd(&sumexp[b], s);
    }
    __syncthreads();

    // bf16 pack + swizzled xT write: thread -> (xs = t>>2, chunk quad q = t&3)
    {
        int xs = t >> 2, q = t & 3;
        u16* dst = xT + ((size_t)b * 4096 + y * 64 + xs) * 128;
        int sw = xs & 7;
#pragma unroll
        for (int k = 0; k < 4; ++k) {
            int cd = q * 4 + k;
            int cs = cd ^ sw;
            u16 tmp[8];
#pragma unroll
            for (int e2 = 0; e2 < 8; ++e2) {
                __hip_bfloat16 h = __float2bfloat16(tile[(cd * 8 + e2) * 68 + xs]);
                tmp[e2] = *reinterpret_cast<u16*>(&h);
            }
            *(int4v*)(dst + cs * 8) = *(int4v*)tmp;
        }
    }

    // context partials: thread -> (ci = t>>1, xs-half = t&1), fp32 from tile
    {
        int ci = t >> 1, half = t & 1;
        float a = 0.f;
#pragma unroll
        for (int j = 0; j < 32; ++j) {
            int xs = half * 32 + j;
            a = fmaf(tile[ci * 68 + xs], e_sh[xs], a);
        }
        a += __shfl_xor(a, 1);
        if (half == 0) atomicAdd(&ctxU[b * 128 + ci], a);
    }
}

// ---------------- Kernel 2: transform (4 threads) + weight generation ----------------
// wgen[b][p] plane (32KB) as 16B units: unit(co,c) = (co>>5)*512 + c*32 + (co&31),
// unit holds bf16 for ci octet c of output row co (A-fragment-coalesced for k_conv).
__global__ __launch_bounds__(256) void k_genw(const float* __restrict__ ctxU,
                                              const float* __restrict__ sumexp,
                                              const float* __restrict__ t1_w,
                                              const float* __restrict__ t1_b,
                                              const float* __restrict__ ln_g,
                                              const float* __restrict__ ln_b,
                                              const float* __restrict__ t2_w,
                                              const float* __restrict__ t2_b,
                                              const float* __restrict__ fc_w,
                                              const float* __restrict__ fc_b,
                                              u16* __restrict__ wgen) {
    int bid = blockIdx.x;
    int b = bid >> 6, c64 = bid & 63;   // block covers co in {c64*2, c64*2+1}, all ci
    int t = threadIdx.x;
    __shared__ float ctx_sh[128];
    __shared__ float traw[RC];
    __shared__ float gate_sh[4];
    if (t < 128) ctx_sh[t] = ctxU[b * 128 + t] / sumexp[b];
    __syncthreads();
    if (t < RC) {
        float a = 0.f;
        for (int c = 0; c < 128; ++c) a = fmaf(ctx_sh[c], t1_w[t * 128 + c], a);
        traw[t] = a + t1_b[t];
    }
    __syncthreads();
    if (t < 4) {
        float tv[RC], mu = 0.f;
#pragma unroll
        for (int r = 0; r < RC; ++r) { tv[r] = traw[r]; mu += tv[r]; }
        mu *= (1.f / RC);
        float var = 0.f;
#pragma unroll
        for (int r = 0; r < RC; ++r) { float d = tv[r] - mu; var = fmaf(d, d, var); }
        var *= (1.f / RC);
        float rs = rsqrtf(var + EPS);
        int gi = (c64 * 2 + (t >> 1)) * 2 + (t & 1);   // t2 row = 2*co + half
        float xw = 0.f;
#pragma unroll
        for (int r = 0; r < RC; ++r) {
            float a = fmaxf(0.f, fmaf((tv[r] - mu) * rs, ln_g[r], ln_b[r]));
            xw = fmaf(a, t2_w[gi * RC + r], xw);
        }
        xw += t2_b[gi];
        gate_sh[t] = 1.f / (1.f + __expf(-xw));
    }
    __syncthreads();
    int co = c64 * 2 + (t >> 7);
    int ci = t & 127;
    float gate = gate_sh[(t >> 7) * 2 + (ci >> 6)];
    const float* wp = fc_w + co * 1152 + ci * 9;
    const float* bp = fc_b + co * 1152 + ci * 9;
    u16* wb = wgen + (size_t)b * 9 * 16384;
    int unit = (co >> 5) * 512 + (ci >> 3) * 32 + (co & 31);
    u16* ubase = wb + unit * 8 + (ci & 7);
#pragma unroll
    for (int p = 0; p < 9; ++p) {
        float v = fmaf(wp[p], gate, bp[p]);
        __hip_bfloat16 h = __float2bfloat16(v);
        ubase[(size_t)p * 16384] = *reinterpret_cast<u16*>(&h);
    }
}

// ---------------- Kernel 3: per-sample 3x3 conv; stage B once, 9 planes barrier-free ----------------
__global__ __launch_bounds__(256, 2) void k_conv(const u16* __restrict__ xT,
                                                 const u16* __restrict__ wgen,
                                                 float* __restrict__ out) {
    __shared__ __align__(16) u16 Bt[4 * 66 * 128];   // 4 y-rows x 66 halo slots x 256B = 67584 B

    int bid0 = blockIdx.x;
    int xcd = bid0 & 7, i5 = bid0 >> 3;
    int b = xcd * 4 + (i5 >> 5);
    int yp = i5 & 31, y0 = yp * 2;

    int t = threadIdx.x;
    int lane = t & 63, w = t >> 6;
    int wr = w >> 1, wc = w & 1;
    int l31 = lane & 31, l5 = lane >> 5;

    const char* xb = (const char*)(xT + (size_t)b * HWSZ * 128);
    const char* wbase = (const char*)(wgen + (size_t)b * 9 * 16384);
    const char* abase = wbase + wr * 16384 + l5 * 512 + l31 * 16;

    bf16x8 RA[16], RB[16];
    f32x16 acc00 = {0}, acc01 = {0}, acc10 = {0}, acc11 = {0};
    char* Bb = (char*)Bt;

#define LOADP(P, R)                                                        \
    {                                                                      \
        const char* ap = abase + (P) * 32768;                              \
        _Pragma("unroll") for (int ks = 0; ks < 8; ++ks) {                 \
            R[ks]     = *(const bf16x8*)(ap + ks * 1024);                  \
            R[8 + ks] = *(const bf16x8*)(ap + 8192 + ks * 1024);           \
        }                                                                  \
    }

#define COMPUTE(P, R)                                                               \
    {                                                                               \
        const int kw = (P) % 3;                                                     \
        int rB0 = (wc + (P) / 3) * 16896 + (l31 + kw) * 256;                        \
        int rB1 = rB0 + 8192;                                                       \
        int sB = ((l31 + kw - 1) & 7) << 4;                                         \
        _Pragma("unroll") for (int ks = 0; ks < 8; ++ks) {                          \
            int kb = ks * 32 + l5 * 16;                                             \
            bf16x8 b0 = *(const bf16x8*)(Bb + rB0 + (kb ^ sB));                     \
            bf16x8 b1 = *(const bf16x8*)(Bb + rB1 + (kb ^ sB));                     \
            acc00 = __builtin_amdgcn_mfma_f32_32x32x16_bf16(R[ks], b0, acc00, 0, 0, 0);     \
            acc01 = __builtin_amdgcn_mfma_f32_32x32x16_bf16(R[ks], b1, acc01, 0, 0, 0);     \
            acc10 = __builtin_amdgcn_mfma_f32_32x32x16_bf16(R[8 + ks], b0, acc10, 0, 0, 0); \
            acc11 = __builtin_amdgcn_mfma_f32_32x32x16_bf16(R[8 + ks], b1, acc11, 0, 0, 0); \
        }                                                                           \
    }

    LOADP(0, RA);   // prefetch plane 0; completes under the staging drain

    // ---- stage all 4 B rows (whole-block DMA), once
    // one y-row = 64 slots x 256B = 16384 B = 4 iters x 256 thr x 16 B
#pragma unroll
    for (int R = 0; R < 4; ++R) {
        int y = y0 + R - 1;
        char* base = Bb + R * 16896;
        if ((unsigned)y < 64u) {
            const char* src = xb + (size_t)y * 16384;
#pragma unroll
            for (int i = 0; i < 4; ++i) {
                int off = (i * 256 + t) * 16;
                dma16(src + off, base + 256 + off);
            }
        } else {
            for (int i = t; i < 1056; i += 256)
                *(int4v*)(base + i * 16) = int4v{0, 0, 0, 0};
        }
    }
    if (t < 128) {   // halo columns (slots 0 and 65) -> zeros
        int R = t >> 5, side = (t >> 4) & 1, c = t & 15;
        *(int4v*)(Bb + R * 16896 + side * 16640 + c * 16) = int4v{0, 0, 0, 0};
    }
    __syncthreads();   // single drain (vmcnt+lgkm) for the whole block

    // ---- 9 planes, no further barriers; A double-buffered in registers
#pragma unroll
    for (int p = 0; p < 9; ++p) {
        if (p < 8) {
            if (p & 1) { LOADP(p + 1, RA); } else { LOADP(p + 1, RB); }
        }
        if (p & 1) { COMPUTE(p, RB); } else { COMPUTE(p, RA); }
    }

    // ---- writeout: C/D layout col=lane&31, row=(reg&3)+8*(reg>>2)+4*(lane>>5)
    float* ob = out + (size_t)b * COUT * HWSZ;
    int y = y0 + wc;
    auto store_acc = [&](const f32x16& v, int m2, int n4) {
        float* colp = ob + (size_t)(wr * 64 + m2 * 32) * HWSZ + y * 64 + n4 * 32 + l31;
#pragma unroll
        for (int r = 0; r < 16; ++r) {
            int row32 = (r & 3) + ((r >> 2) << 3) + (l5 << 2);
            colp[(size_t)row32 * HWSZ] = v[r];
        }
    };
    store_acc(acc00, 0, 0);
    store_acc(acc01, 0, 1);
    store_acc(acc10, 1, 0);
    store_acc(acc11, 1, 1);
#undef LOADP
#undef COMPUTE
}

extern "C" void kernel_launch(void* const* d_in, const int* in_sizes, int n_in,
                              void* d_out, int out_size, void* d_ws, size_t ws_size,
                              hipStream_t stream) {
    const float* x      = (const float*)d_in[0];
    const float* mask_w = (const float*)d_in[1];
    const float* mask_b = (const float*)d_in[2];
    const float* t1_w   = (const float*)d_in[3];
    const float* t1_b   = (const float*)d_in[4];
    const float* ln_g   = (const float*)d_in[5];
    const float* ln_b   = (const float*)d_in[6];
    const float* t2_w   = (const float*)d_in[7];
    const float* t2_b   = (const float*)d_in[8];
    const float* fc_w   = (const float*)d_in[9];
    const float* fc_b   = (const float*)d_in[10];
    float* out = (float*)d_out;

    char* ws = (char*)d_ws;
    u16*   xT     = (u16*)ws;                        // 33,554,432 B
    float* ctxU   = (float*)(ws + 33554432);         // 16,384 B (unnormalized context)
    float* sumexp = (float*)(ws + 33570816);         // 128 B (padded to 1024)
    u16*   wgen   = (u16*)(ws + 33571840);           // 9,437,184 B  (total ~43 MB)

    hipMemsetAsync(ws + 33554432, 0, 17408, stream);  // zero ctxU + sumexp

    k_xform<<<dim3(64, 32), 256, 0, stream>>>(x, mask_w, mask_b, xT, ctxU, sumexp);
    k_genw <<<2048, 256, 0, stream>>>(ctxU, sumexp, t1_w, t1_b, ln_g, ln_b,
                                      t2_w, t2_b, fc_w, fc_b, wgen);
    k_conv <<<1024, 256, 0, stream>>>(xT, wgen, out);
}